// Round 1
// baseline (322.017 us; speedup 1.0000x reference)
//
#include <hip/hip_runtime.h>

// DWTExtractor: level-1 + level-2 Haar DWT, level-2 details bilinearly upsampled 2x.
// Input x: (B,1,1024,1024) fp32. Output: (B,6,512,512) fp32.

#define HW_IN 1024
#define HW_L1 512
#define HW_L2 256

// Kernel 1: level-1 Haar. One thread = 2 output columns (float4 input loads).
// Writes cH1,cV1,cD1 to out channels 0..2, cA1 to workspace (if WRITE_A).
template <bool WRITE_A>
__global__ __launch_bounds__(256) void dwt_l1_kernel(const float* __restrict__ x,
                                                     float* __restrict__ out,
                                                     float* __restrict__ cA)
{
    int idx = blockIdx.x * blockDim.x + threadIdx.x;   // B * 512 * 256 threads
    int jj = idx & 255;            // float4 index within row (covers cols 4*jj..4*jj+3)
    int t  = idx >> 8;
    int i  = t & 511;              // level-1 row
    int b  = t >> 9;

    const float* xb = x + ((size_t)b << 20);
    const float4 r0 = ((const float4*)(xb + ((size_t)(2 * i)     << 10)))[jj];
    const float4 r1 = ((const float4*)(xb + ((size_t)(2 * i + 1) << 10)))[jj];

    float a0 = (r0.x + r0.y + r1.x + r1.y) * 0.5f;
    float h0 = (r0.x - r0.y + r1.x - r1.y) * 0.5f;
    float v0 = (r0.x + r0.y - r1.x - r1.y) * 0.5f;
    float d0 = (r0.x - r0.y - r1.x + r1.y) * 0.5f;
    float a1 = (r0.z + r0.w + r1.z + r1.w) * 0.5f;
    float h1 = (r0.z - r0.w + r1.z - r1.w) * 0.5f;
    float v1 = (r0.z + r0.w - r1.z - r1.w) * 0.5f;
    float d1 = (r0.z - r0.w - r1.z + r1.w) * 0.5f;

    const size_t plane  = (size_t)HW_L1 * HW_L1;       // 262144
    const size_t rowoff = (size_t)i * HW_L1 + 2 * jj;
    float* ob = out + (size_t)b * 6 * plane;
    *(float2*)(ob + 0 * plane + rowoff) = make_float2(h0, h1);
    *(float2*)(ob + 1 * plane + rowoff) = make_float2(v0, v1);
    *(float2*)(ob + 2 * plane + rowoff) = make_float2(d0, d1);
    if (WRITE_A)
        *(float2*)(cA + (size_t)b * plane + rowoff) = make_float2(a0, a1);
}

// Kernel 2: level-2 Haar (from cA1) + 2x bilinear upsample (half-pixel, clamped
// edges == jax renormalized weights for exact 2x). One thread = one output pixel
// across channels 3..5.
template <bool USE_WS>
__global__ __launch_bounds__(256) void dwt_l2_up_kernel(const float* __restrict__ x,
                                                        const float* __restrict__ cA,
                                                        float* __restrict__ out)
{
    int j = blockIdx.x * 16 + threadIdx.x;   // output col in [0,512)
    int i = blockIdx.y * 16 + threadIdx.y;   // output row in [0,512)
    int b = blockIdx.z;

    // half-pixel source coords: s = o*0.5 - 0.25
    int   p0 = (i - 1) >> 1;                 // floor(s_i)
    int   p1 = p0 + 1;
    float fi = (i & 1) ? 0.25f : 0.75f;      // weight of p1
    int   q0 = (j - 1) >> 1;
    int   q1 = q0 + 1;
    float fj = (j & 1) ? 0.25f : 0.75f;
    p0 = max(p0, 0); p1 = min(p1, HW_L2 - 1);
    q0 = max(q0, 0); q1 = min(q1, HW_L2 - 1);

    auto getA = [&](int r, int c) -> float {  // cA1[b][r][c], r,c in [0,512)
        if (USE_WS)
            return cA[((size_t)b << 18) + ((size_t)r << 9) + c];
        const float* xb = x + ((size_t)b << 20) + ((size_t)(2 * r) << 10) + 2 * c;
        return (xb[0] + xb[1] + xb[HW_IN] + xb[HW_IN + 1]) * 0.5f;
    };

    float h[2][2], v[2][2], d[2][2];
    int ps[2] = {p0, p1}, qs[2] = {q0, q1};
#pragma unroll
    for (int pi = 0; pi < 2; ++pi) {
#pragma unroll
        for (int qi = 0; qi < 2; ++qi) {
            int p = ps[pi], q = qs[qi];
            float a00 = getA(2 * p,     2 * q);
            float a01 = getA(2 * p,     2 * q + 1);
            float a10 = getA(2 * p + 1, 2 * q);
            float a11 = getA(2 * p + 1, 2 * q + 1);
            h[pi][qi] = (a00 - a01 + a10 - a11) * 0.5f;
            v[pi][qi] = (a00 + a01 - a10 - a11) * 0.5f;
            d[pi][qi] = (a00 - a01 - a10 + a11) * 0.5f;
        }
    }

    float w00 = (1.f - fi) * (1.f - fj), w01 = (1.f - fi) * fj;
    float w10 = fi * (1.f - fj),         w11 = fi * fj;

    float H = w00 * h[0][0] + w01 * h[0][1] + w10 * h[1][0] + w11 * h[1][1];
    float V = w00 * v[0][0] + w01 * v[0][1] + w10 * v[1][0] + w11 * v[1][1];
    float D = w00 * d[0][0] + w01 * d[0][1] + w10 * d[1][0] + w11 * d[1][1];

    const size_t plane = (size_t)HW_L1 * HW_L1;
    float* ob = out + (size_t)b * 6 * plane + (size_t)i * HW_L1 + j;
    ob[3 * plane] = H;
    ob[4 * plane] = V;
    ob[5 * plane] = D;
}

extern "C" void kernel_launch(void* const* d_in, const int* in_sizes, int n_in,
                              void* d_out, int out_size, void* d_ws, size_t ws_size,
                              hipStream_t stream)
{
    const float* x = (const float*)d_in[0];
    float* out = (float*)d_out;
    float* cA  = (float*)d_ws;

    int B = in_sizes[0] >> 20;  // elems / (1024*1024)
    size_t ws_needed = (size_t)B * HW_L1 * HW_L1 * sizeof(float);
    bool use_ws = (ws_size >= ws_needed);

    int n1 = B * HW_L1 * (HW_L1 / 2);   // 2 cols per thread
    dim3 grid2((HW_L1 + 15) / 16, (HW_L1 + 15) / 16, B);
    dim3 block2(16, 16, 1);

    if (use_ws) {
        dwt_l1_kernel<true><<<n1 / 256, 256, 0, stream>>>(x, out, cA);
        dwt_l2_up_kernel<true><<<grid2, block2, 0, stream>>>(x, cA, out);
    } else {
        dwt_l1_kernel<false><<<n1 / 256, 256, 0, stream>>>(x, out, nullptr);
        dwt_l2_up_kernel<false><<<grid2, block2, 0, stream>>>(x, nullptr, out);
    }
}

// Round 3
// 311.997 us; speedup vs baseline: 1.0321x; 1.0321x over previous
//
#include <hip/hip_runtime.h>

// DWTExtractor fused: level-1 Haar (cH1,cV1,cD1 -> ch 0..2) + level-2 Haar on
// cA1 staged in LDS + 2x half-pixel bilinear upsample (-> ch 3..5).
// Input x: (B,1,1024,1024) fp32. Output: (B,6,512,512) fp32. One kernel.

#define HW_L1 512
#define PLANE ((size_t)HW_L1 * HW_L1)
#define TILE 64           // level-1 tile per block
#define LH 68             // TILE + 2 halo each side
#define LW 70             // padded LDS row stride (floats, even for float2 align)

__global__ __launch_bounds__(256) void dwt_fused_kernel(const float* __restrict__ x,
                                                        float* __restrict__ out)
{
    __shared__ float lds[LH * LW];

    const int tid = threadIdx.x;
    const int b  = blockIdx.z;
    const int i0 = blockIdx.y * TILE;   // level-1 row origin
    const int j0 = blockIdx.x * TILE;   // level-1 col origin

    const float* xb = x + ((size_t)b << 20);
    float* ob = out + (size_t)b * 6 * PLANE;

    // ---- Phase 1a: interior level-1. 32 float4-cols x 8 rows, 8 iterations.
    {
        const int tx = tid & 31;        // float4 column within tile
        const int ty = tid >> 5;        // row sub-index
        const int f4 = (j0 >> 1) + tx;  // global float4 column index
#pragma unroll
        for (int k = 0; k < 8; ++k) {
            const int il = k * 8 + ty;          // 0..63 local L1 row
            const int i  = i0 + il;
            const float4 r0 = ((const float4*)(xb + ((size_t)(2 * i)     << 10)))[f4];
            const float4 r1 = ((const float4*)(xb + ((size_t)(2 * i + 1) << 10)))[f4];

            const float a0 = (r0.x + r0.y + r1.x + r1.y) * 0.5f;
            const float h0 = (r0.x - r0.y + r1.x - r1.y) * 0.5f;
            const float v0 = (r0.x + r0.y - r1.x - r1.y) * 0.5f;
            const float d0 = (r0.x - r0.y - r1.x + r1.y) * 0.5f;
            const float a1 = (r0.z + r0.w + r1.z + r1.w) * 0.5f;
            const float h1 = (r0.z - r0.w + r1.z - r1.w) * 0.5f;
            const float v1 = (r0.z + r0.w - r1.z - r1.w) * 0.5f;
            const float d1 = (r0.z - r0.w - r1.z + r1.w) * 0.5f;

            const size_t ro = (size_t)i * HW_L1 + j0 + 2 * tx;
            *(float2*)(ob + 0 * PLANE + ro) = make_float2(h0, h1);
            *(float2*)(ob + 1 * PLANE + ro) = make_float2(v0, v1);
            *(float2*)(ob + 2 * PLANE + ro) = make_float2(d0, d1);
            *(float2*)(&lds[(il + 2) * LW + 2 * tx + 2]) = make_float2(a0, a1);
        }
    }

    // ---- Phase 1b: halo cA1 (2 rows/cols around tile), 528 cells, scalar.
    for (int c = tid; c < 528; c += 256) {
        int lr, lc;
        if (c < 136)      { lr = c / 68;                lc = c % 68; }
        else if (c < 272) { lr = 66 + (c - 136) / 68;   lc = (c - 136) % 68; }
        else { int s = c - 272; lr = 2 + (s >> 2); int m = s & 3; lc = (m < 2) ? m : 64 + m; }
        const int gi = min(max(i0 + lr - 2, 0), HW_L1 - 1);
        const int gj = min(max(j0 + lc - 2, 0), HW_L1 - 1);
        const float* p = xb + ((size_t)(2 * gi) << 10) + 2 * gj;
        lds[lr * LW + lc] = (p[0] + p[1] + p[1024] + p[1025]) * 0.5f;
    }

    __syncthreads();

    // ---- Phase 2: level-2 Haar from LDS cA1 + 2x bilinear, ch 3..5.
    {
        const int jl = tid & 63;
        const int j  = j0 + jl;
        // half-pixel 2x: s = j/2 - 0.25; taps floor(s), floor(s)+1 (then clamp BOTH)
        const int q0u = (j - 1) >> 1;
        const int q1  = min(q0u + 1, 255);   // from UNCLAMPED q0 (edge renorm == clamp)
        const int q0  = max(q0u, 0);
        const float fj = (j & 1) ? 0.25f : 0.75f;   // weight of q1 tap
        const int c0 = 2 * q0 - j0 + 2;   // local col of A(:,2q0), even
        const int c1 = 2 * q1 - j0 + 2;

#pragma unroll
        for (int k = 0; k < 16; ++k) {
            const int il = k * 4 + (tid >> 6);
            const int i  = i0 + il;
            const int p0u = (i - 1) >> 1;
            const int p1  = min(p0u + 1, 255);
            const int p0  = max(p0u, 0);
            const float fi = (i & 1) ? 0.25f : 0.75f;
            const int ra = 2 * p0 - i0 + 2;   // local rows ra, ra+1
            const int rb = 2 * p1 - i0 + 2;   // local rows rb, rb+1

            const float2 t00 = *(const float2*)&lds[ra * LW + c0];       // row 2p0, cols 2q0..
            const float2 t01 = *(const float2*)&lds[ra * LW + c1];
            const float2 t10 = *(const float2*)&lds[(ra + 1) * LW + c0]; // row 2p0+1
            const float2 t11 = *(const float2*)&lds[(ra + 1) * LW + c1];
            const float2 u00 = *(const float2*)&lds[rb * LW + c0];       // row 2p1
            const float2 u01 = *(const float2*)&lds[rb * LW + c1];
            const float2 u10 = *(const float2*)&lds[(rb + 1) * LW + c0]; // row 2p1+1
            const float2 u11 = *(const float2*)&lds[(rb + 1) * LW + c1];

            // per (p,q): sm = a00-a01 (top), sp = a00+a01; h=(sm_t+sm_b)/2, v=(sp_t-sp_b)/2, d=(sm_t-sm_b)/2
            const float sm_t0 = t00.x - t00.y, sp_t0 = t00.x + t00.y;
            const float sm_b0 = t10.x - t10.y, sp_b0 = t10.x + t10.y;
            const float sm_t1 = t01.x - t01.y, sp_t1 = t01.x + t01.y;
            const float sm_b1 = t11.x - t11.y, sp_b1 = t11.x + t11.y;
            const float sm_T0 = u00.x - u00.y, sp_T0 = u00.x + u00.y;
            const float sm_B0 = u10.x - u10.y, sp_B0 = u10.x + u10.y;
            const float sm_T1 = u01.x - u01.y, sp_T1 = u01.x + u01.y;
            const float sm_B1 = u11.x - u11.y, sp_B1 = u11.x + u11.y;

            const float h00 = (sm_t0 + sm_b0) * 0.5f, v00 = (sp_t0 - sp_b0) * 0.5f, d00 = (sm_t0 - sm_b0) * 0.5f;
            const float h01 = (sm_t1 + sm_b1) * 0.5f, v01 = (sp_t1 - sp_b1) * 0.5f, d01 = (sm_t1 - sm_b1) * 0.5f;
            const float h10 = (sm_T0 + sm_B0) * 0.5f, v10 = (sp_T0 - sp_B0) * 0.5f, d10 = (sm_T0 - sm_B0) * 0.5f;
            const float h11 = (sm_T1 + sm_B1) * 0.5f, v11 = (sp_T1 - sp_B1) * 0.5f, d11 = (sm_T1 - sm_B1) * 0.5f;

            const float w00 = (1.f - fi) * (1.f - fj), w01 = (1.f - fi) * fj;
            const float w10 = fi * (1.f - fj),         w11 = fi * fj;

            const float H = w00 * h00 + w01 * h01 + w10 * h10 + w11 * h11;
            const float V = w00 * v00 + w01 * v01 + w10 * v10 + w11 * v11;
            const float D = w00 * d00 + w01 * d01 + w10 * d10 + w11 * d11;

            const size_t oo = (size_t)i * HW_L1 + j;
            ob[3 * PLANE + oo] = H;
            ob[4 * PLANE + oo] = V;
            ob[5 * PLANE + oo] = D;
        }
    }
}

extern "C" void kernel_launch(void* const* d_in, const int* in_sizes, int n_in,
                              void* d_out, int out_size, void* d_ws, size_t ws_size,
                              hipStream_t stream)
{
    const float* x = (const float*)d_in[0];
    float* out = (float*)d_out;
    const int B = in_sizes[0] >> 20;   // elems / (1024*1024)

    dim3 grid(HW_L1 / TILE, HW_L1 / TILE, B);   // 8 x 8 x B
    dwt_fused_kernel<<<grid, 256, 0, stream>>>(x, out);
}